// Round 7
// baseline (136.716 us; speedup 1.0000x reference)
//
#include <hip/hip_runtime.h>
#include <math.h>

// CrossAttention B=2, Sq=Sk=2048, H=16, Hkv=4, D=64, fp32 io.
// R7: QT=64, 1024 main blocks (4/CU, 16 waves/CU), 32x32x16 MFMA with the
// tile split 2D across waves: wave(qh,kh) owns S^T[key 32][qrow 32], P stays
// wave-private, kh-partial O summed once in epilogue via LDS. Fixed-shift
// exp2 softmax, ballot pad mask, 66-tile/slot balance, fixup blocks first.

typedef __bf16 bf16x4 __attribute__((ext_vector_type(4)));
typedef __bf16 bf16x8 __attribute__((ext_vector_type(8)));
typedef float floatx4 __attribute__((ext_vector_type(4)));
typedef float floatx16 __attribute__((ext_vector_type(16)));

#define B_ 2
#define SQ 2048
#define SK 2048
#define H_ 16
#define HKV 4
#define D_ 64
#define QT 64
#define KT 64
#define PADK 72             // K/V LDS rows: 144B
#define PADP 40             // P LDS rows: 80B (16B-aligned)
#define KVROW 512
#define NEGV (-10000.0f)
#define QSCL 0.18033688f    // 0.125 * log2(e)
#define EBIAS 17.3123405f

__global__ __launch_bounds__(256, 4)
void attn_kernel(const float* __restrict__ q,
                 const float* __restrict__ kv,
                 const int* __restrict__ mask,
                 float* __restrict__ out)
{
    __shared__ union {
        struct { __bf16 Kt[KT][PADK]; __bf16 Vt[D_][PADK]; } m;  // main loop
        float Ored[2][32][64];                                   // epilogue
        struct { float part[4][64]; float w[4][64]; } f;         // fixup
    } u;
    __shared__ alignas(16) __bf16 Pl[4][32][PADP];
    __shared__ float lpart[2][2][32];
    __shared__ float linv[2][32];
    __shared__ int s_first;

    const int tid  = threadIdx.x;
    const int wave = tid >> 6;
    const int lane = tid & 63;
    const int half = lane >> 5;
    const int nn   = lane & 31;

    if (blockIdx.x < 32) {
        // ================= fixup role: rows R < first_kept[b] ===============
        const int bh = (int)blockIdx.x;
        const int b = bh >> 4, h = bh & 15, hkv = h >> 2;
        if (tid == 0) s_first = SK;
        __syncthreads();
        int local = SK;
        for (int s = tid; s < SK; s += 256)
            if (mask[b * SK + s]) local = min(local, s);
        atomicMin(&s_first, local);
        __syncthreads();
        const int nfirst = s_first;
        if (nfirst == 0) return;

        const float* kvb = kv + (size_t)b * SK * KVROW + hkv * D_;
        const float* vvb = kvb + HKV * D_;
        {
            float a0=0,a1=0,a2=0,a3=0,a4=0,a5=0,a6=0,a7=0;
            const int s0 = wave * 512;
            for (int s = s0; s < s0 + 512; s += 8) {
                a0 += vvb[(size_t)(s+0)*KVROW + lane];
                a1 += vvb[(size_t)(s+1)*KVROW + lane];
                a2 += vvb[(size_t)(s+2)*KVROW + lane];
                a3 += vvb[(size_t)(s+3)*KVROW + lane];
                a4 += vvb[(size_t)(s+4)*KVROW + lane];
                a5 += vvb[(size_t)(s+5)*KVROW + lane];
                a6 += vvb[(size_t)(s+6)*KVROW + lane];
                a7 += vvb[(size_t)(s+7)*KVROW + lane];
            }
            u.f.part[wave][lane] = ((a0+a1)+(a2+a3)) + ((a4+a5)+(a6+a7));
        }
        __syncthreads();
        const float vtotal = u.f.part[0][lane] + u.f.part[1][lane]
                           + u.f.part[2][lane] + u.f.part[3][lane];

        for (int R = wave; R < nfirst; R += 4) {
            const float* qrow = q + (((size_t)b * SQ + R) * H_ + h) * D_;
            float mymax = -3.4e38f;
            for (int s = lane; s <= R; s += 64) {
                const float* kp = kvb + (size_t)s * KVROW;
                float dt = 0.f;
                for (int d = 0; d < D_; ++d) dt += qrow[d] * kp[d];
                mymax = fmaxf(mymax, dt * 0.125f + NEGV);
            }
#pragma unroll
            for (int off = 32; off >= 1; off >>= 1)
                mymax = fmaxf(mymax, __shfl_xor(mymax, off, 64));
            const float M = (R < SK - 1) ? fmaxf(mymax, NEGV) : mymax;
            float lsum = 0.f, oacc = 0.f, pref = 0.f;
            for (int s0 = 0; s0 <= R; s0 += 64) {
                int s = s0 + lane;
                float w = 0.f;
                if (s <= R) {
                    const float* kp = kvb + (size_t)s * KVROW;
                    float dt = 0.f;
                    for (int d = 0; d < D_; ++d) dt += qrow[d] * kp[d];
                    w = __expf(dt * 0.125f + NEGV - M);
                    lsum += w;
                }
                u.f.w[wave][lane] = w;   // wave-private, in-order
                const int nk = (R - s0 + 1 < 64) ? (R - s0 + 1) : 64;
                for (int j = 0; j < nk; ++j) {
                    const float vj = vvb[(size_t)(s0 + j) * KVROW + lane];
                    oacc += u.f.w[wave][j] * vj;
                    pref += vj;
                }
            }
#pragma unroll
            for (int off = 32; off >= 1; off >>= 1)
                lsum += __shfl_xor(lsum, off, 64);
            const float wn   = __expf(NEGV - M);
            const float ltot = lsum + wn * (float)(SK - 1 - R);
            out[(((size_t)b * SQ + R) * H_ + h) * D_ + lane] =
                (oacc + wn * (vtotal - pref)) / ltot;
        }
        return;
    }

    // ================= main attention role ==================================
    const int id = (int)blockIdx.x - 32;
    const int bh = id & 31;
    const int y  = id >> 5;               // 0..31
    const int kg = y >> 3, jj = y & 7;    // quad {31-j, j, 23-j, 8+j}: 66 tiles
    const int qt = (kg == 0) ? 31 - jj : (kg == 1) ? jj : (kg == 2) ? 23 - jj : 8 + jj;
    const int b = bh >> 4, h = bh & 15, hkv = h >> 2;
    const int q0 = qt * QT;

    const int qh = wave & 1;              // q-row sub-tile (32)
    const int kh = wave >> 1;             // key sub-tile (32)
    const int qrow_g = q0 + qh * 32 + nn; // this lane's S^T column

    // ---- Q B-fragments (n=qrow, k=d), exp2-prescaled ----
    bf16x8 bq[4];
    {
        const float* qp = q + (((size_t)b * SQ + qrow_g) * H_ + h) * D_;
#pragma unroll
        for (int ks = 0; ks < 4; ++ks)
#pragma unroll
            for (int j = 0; j < 8; ++j)
                bq[ks][j] = (__bf16)(qp[ks * 16 + half * 8 + j] * QSCL);
    }

    floatx16 o0, o1;                      // O partial [qrow32][d32] x2 (this kh)
#pragma unroll
    for (int i = 0; i < 16; ++i) { o0[i] = 0.f; o1[i] = 0.f; }
    float lsum = 0.f;

    const int kkey = tid >> 4;
    const int kd   = (tid & 15) * 4;
    const int vkey = (tid & 15) * 4;
    const int vd   = (tid >> 4) * 4;

    const float* kvb = kv + (size_t)b * SK * KVROW + hkv * D_;

    float4 kreg[4], vreg[4];
    int mreg = 0;

    auto prefetch = [&](int kt) {
        const float* kb = kvb + (size_t)kt * KT * KVROW;
#pragma unroll
        for (int i = 0; i < 4; ++i)
            kreg[i] = *(const float4*)(kb + (kkey + 16 * i) * KVROW + kd);
        const float* vb = kb + HKV * D_;
#pragma unroll
        for (int i = 0; i < 4; ++i)
            vreg[i] = *(const float4*)(vb + (vkey + i) * KVROW + vd);
        mreg = mask[b * SK + kt * KT + lane];
    };

    auto stage = [&]() {
#pragma unroll
        for (int i = 0; i < 4; ++i) {
            bf16x4 t = { (__bf16)kreg[i].x, (__bf16)kreg[i].y,
                         (__bf16)kreg[i].z, (__bf16)kreg[i].w };
            *(bf16x4*)&u.m.Kt[kkey + 16 * i][kd] = t;
        }
        const float* vf = (const float*)vreg;
#pragma unroll
        for (int j = 0; j < 4; ++j) {
            bf16x4 t = { (__bf16)vf[0*4+j], (__bf16)vf[1*4+j],
                         (__bf16)vf[2*4+j], (__bf16)vf[3*4+j] };
            *(bf16x4*)&u.m.Vt[vd + j][vkey] = t;
        }
    };

    const int nkt = qt + 1;
    prefetch(0);

    for (int kt = 0; kt < nkt; ++kt) {
        stage();
        const unsigned long long kept = __ballot(mreg != 0);
        __syncthreads();
        if (kt + 1 < nkt) prefetch(kt + 1);

        const int k0 = kt * KT;
        const bool dg = (kt == qt);
        if (!(dg && wave == 2)) {         // (kh=1,qh=0) on diag: fully masked
            // ---- S^T = K * Q^T : [m=key32 (kh)][n=qrow32 (qh)] ----
            floatx16 cst;
#pragma unroll
            for (int i = 0; i < 16; ++i) cst[i] = 0.f;
#pragma unroll
            for (int ks = 0; ks < 4; ++ks) {
                bf16x8 ak = *(const bf16x8*)&u.m.Kt[kh*32 + nn][ks*16 + half*8];
                cst = __builtin_amdgcn_mfma_f32_32x32x16_bf16(ak, bq[ks], cst, 0, 0, 0);
            }
            // ---- mask + exp2 + packed wave-private P store ----
#pragma unroll
            for (int g = 0; g < 4; ++g) {
                const int mloc = 8*g + 4*half;            // key within kh-half
                const unsigned bits = (unsigned)(kept >> (kh*32 + mloc));
                bf16x4 pk;
#pragma unroll
                for (int r = 0; r < 4; ++r) {
                    float p = __builtin_amdgcn_exp2f(cst[g*4 + r] - EBIAS);
                    if (!((bits >> r) & 1u)) p = 0.f;                  // pad
                    if (dg && (k0 + kh*32 + mloc + r > qrow_g)) p = 0.f; // causal
                    lsum += p;
                    pk[r] = (__bf16)p;
                }
                *(bf16x4*)&Pl[wave][nn][mloc] = pk;
            }
            // ---- O += P * V over this kh's 32 keys ----
            bf16x8 ap[2];
#pragma unroll
            for (int ks2 = 0; ks2 < 2; ++ks2)
                ap[ks2] = *(const bf16x8*)&Pl[wave][nn][ks2*16 + half*8];
#pragma unroll
            for (int ks2 = 0; ks2 < 2; ++ks2) {
                bf16x8 bv0 = *(const bf16x8*)&u.m.Vt[nn][kh*32 + ks2*16 + half*8];
                o0 = __builtin_amdgcn_mfma_f32_32x32x16_bf16(ap[ks2], bv0, o0, 0, 0, 0);
                bf16x8 bv1 = *(const bf16x8*)&u.m.Vt[32 + nn][kh*32 + ks2*16 + half*8];
                o1 = __builtin_amdgcn_mfma_f32_32x32x16_bf16(ap[ks2], bv1, o1, 0, 0, 0);
            }
        }
        __syncthreads();
    }

    // ---- epilogue: combine kh partials, normalize, store ----
    lsum += __shfl_xor(lsum, 32, 64);
    lpart[kh][qh][nn] = lsum;
    __syncthreads();                       // also: last Vt reads done (loop sync)
    if (kh == 0) {
        const float l = lpart[0][qh][nn] + lpart[1][qh][nn];
        linv[qh][nn] = (l > 0.f) ? 1.f / l : 0.f;
#pragma unroll
        for (int g = 0; g < 4; ++g)
#pragma unroll
            for (int r = 0; r < 4; ++r) {
                const int m = 4*half + 8*g + r;
                u.Ored[qh][m][nn]      = o0[g*4 + r];
                u.Ored[qh][m][32 + nn] = o1[g*4 + r];
            }
    }
    __syncthreads();
    if (kh == 1) {
#pragma unroll
        for (int g = 0; g < 4; ++g) {
            floatx4 li = *(const floatx4*)&linv[qh][8*g + 4*half];
#pragma unroll
            for (int r = 0; r < 4; ++r) {
                if (li[r] != 0.f) {        // l==0 rows written by fixup
                    const int m = 4*half + 8*g + r;
                    const int row = q0 + qh*32 + m;
                    float* op = out + (((size_t)b * SQ + row) * H_ + h) * D_ + nn;
                    op[0]  = (u.Ored[qh][m][nn]      + o0[g*4 + r]) * li[r];
                    op[32] = (u.Ored[qh][m][32 + nn] + o1[g*4 + r]) * li[r];
                }
            }
        }
    }
}

extern "C" void kernel_launch(void* const* d_in, const int* in_sizes, int n_in,
                              void* d_out, int out_size, void* d_ws, size_t ws_size,
                              hipStream_t stream) {
    const float* q   = (const float*)d_in[0];
    const float* kv  = (const float*)d_in[1];
    const int* mask  = (const int*)d_in[2];
    float* out       = (float*)d_out;
    attn_kernel<<<dim3(32 + 1024), 256, 0, stream>>>(q, kv, mask, out);
}